// Round 6
// baseline (273.861 us; speedup 1.0000x reference)
//
#include <hip/hip_runtime.h>
#include <hip/hip_cooperative_groups.h>
#include <math.h>

namespace cg = cooperative_groups;

#define N_TOT 8400
#define MASK_WORDS 132   // ceil(8400/64)
#define CAP 32           // max (word,bits) entries per row
#define GRID 256         // cooperative grid blocks (256 thr each) -- 1/CU, always co-resident
#define TPAIRS 8778      // 132*133/2 upper-triangle (cw>=rb) tile pairs

typedef unsigned long long u64;

struct MegaParams {
    const float *score0, *bbox0, *kps0;
    const float *score1, *bbox1, *kps1;
    const float *score2, *bbox2, *kps2;
    float *logit, *sig, *box, *kps;
    float *s_logit, *s_sig, *s_box, *s_kps;
    u64 *key;
    int *rank;
    unsigned int *cnt;
    u64 *validw, *rowflag, *keep_words;
    ulonglong2 *ent;
    float *out;
};

// monotone-increasing float->u32 mapping
__device__ __forceinline__ unsigned mono_u32(float f) {
    unsigned u = __float_as_uint(f);
    return (u & 0x80000000u) ? ~u : (u | 0x80000000u);
}

__global__ __launch_bounds__(256) void mega_kernel(MegaParams p) {
    cg::grid_group grid = cg::this_grid();
    const int tid  = threadIdx.x;
    const int gtid = blockIdx.x * 256 + tid;

    __shared__ u64 tileB[256];            // phase B rank tile
    __shared__ unsigned short nlist[8448]; // phase E nonzero-row list

    // ---------------- Phase A: decode + zero-init ----------------
    if (gtid < N_TOT) {
        int i = gtid;
        if (i < MASK_WORDS) { p.validw[i] = 0ull; p.rowflag[i] = 0ull; }
        p.rank[i] = 0;
        p.cnt[i] = 0u;
        const float *sc, *bb, *kp;
        int m, F; float s;
        if (i < 6400)      { sc = p.score0; bb = p.bbox0; kp = p.kps0; m = i;        F = 80; s = 8.f;  }
        else if (i < 8000) { sc = p.score1; bb = p.bbox1; kp = p.kps1; m = i - 6400; F = 40; s = 16.f; }
        else               { sc = p.score2; bb = p.bbox2; kp = p.kps2; m = i - 8000; F = 20; s = 32.f; }
        float px = (float)(m % F) * s;
        float py = (float)(m / F) * s;
        float lg = sc[m];
        p.logit[i] = lg;
        p.sig[i] = 1.0f / (1.0f + expf(-lg));
        p.key[i] = ((u64)(~mono_u32(lg)) << 14) | (u64)i;
        float d0 = bb[m*4+0]*s, d1 = bb[m*4+1]*s, d2 = bb[m*4+2]*s, d3 = bb[m*4+3]*s;
        p.box[i*4+0] = px - d0;
        p.box[i*4+1] = py - d1;
        p.box[i*4+2] = px + d2;
        p.box[i*4+3] = py + d3;
        #pragma unroll
        for (int c = 0; c < 5; ++c) {
            p.kps[i*10 + 2*c]   = px + kp[m*10 + 2*c]   * s;
            p.kps[i*10 + 2*c+1] = py + kp[m*10 + 2*c+1] * s;
        }
    }
    grid.sync();

    // ---------------- Phase B: rank = #{j : key[j] < key[i]} (33x33 tiles) ----------------
    for (int t = blockIdx.x; t < 33 * 33; t += GRID) {
        int bi = t / 33, bj = t % 33;
        int j = bj * 256 + tid;
        tileB[tid] = (j < N_TOT) ? p.key[j] : ~0ull;
        __syncthreads();
        int i = bi * 256 + tid;
        if (i < N_TOT) {
            u64 ki = p.key[i];
            int rk = 0;
            #pragma unroll 8
            for (int k = 0; k < 256; ++k) rk += (tileB[k] < ki) ? 1 : 0;
            if (rk) atomicAdd(&p.rank[i], rk);
        }
        __syncthreads();
    }
    grid.sync();

    // ---------------- Phase C: scatter into sorted order + valid bits ----------------
    if (gtid < N_TOT) {
        int i = gtid;
        int r = p.rank[i];
        float lg = p.logit[i];
        p.s_logit[r] = lg;
        p.s_sig[r] = p.sig[i];
        #pragma unroll
        for (int c = 0; c < 4; ++c)  p.s_box[r*4+c] = p.box[i*4+c];
        #pragma unroll
        for (int c = 0; c < 10; ++c) p.s_kps[r*10+c] = p.kps[i*10+c];
        if (lg > 0.f) atomicOr(&p.validw[r >> 6], 1ull << (r & 63));
    }
    grid.sync();

    // ---------------- Phase D: sparse successor pairs (per-wave tiles, shuffle bcast) ----------------
    {
        int wv = tid >> 6;
        int lane = tid & 63;
        int wgid = blockIdx.x * 4 + wv;
        const float4* sbox4 = (const float4*)p.s_box;
        for (int t = wgid; t < TPAIRS; t += GRID * 4) {
            // triangle decode: t = rb*(265-rb)/2 + (cw-rb)
            int rb = (int)((265.0 - sqrt(70225.0 - 8.0 * (double)t)) * 0.5);
            while (rb > 0 && (rb * (265 - rb)) / 2 > t) --rb;
            while (((rb + 1) * (265 - (rb + 1))) / 2 <= t) ++rb;
            int cw = rb + (t - (rb * (265 - rb)) / 2);

            int j = cw * 64 + lane;
            float4 cb = make_float4(0.f, 0.f, 0.f, 0.f);
            float lgj = -1.f;
            if (j < N_TOT) { cb = sbox4[j]; lgj = p.s_logit[j]; }
            u64 cvalid = __ballot(j < N_TOT && lgj > 0.f);
            if (cvalid == 0ull) continue;

            int r = rb * 64 + lane;
            float lgr = (r < N_TOT) ? p.s_logit[r] : -1.f;
            if (__ballot(lgr > 0.f) == 0ull) continue;

            float4 rb4 = (r < N_TOT) ? sbox4[r] : make_float4(0.f, 0.f, 0.f, 0.f);
            float rarea = (rb4.z - rb4.x) * (rb4.w - rb4.y);
            float ca = (cb.z - cb.x) * (cb.w - cb.y);
            u64 bits = 0ull;
            #pragma unroll 4
            for (int k = 0; k < 64; ++k) {   // all lanes active -> shfl well-defined
                float cx1 = __shfl(cb.x, k);
                float cy1 = __shfl(cb.y, k);
                float cx2 = __shfl(cb.z, k);
                float cy2 = __shfl(cb.w, k);
                float cak = __shfl(ca, k);
                float ltx = fmaxf(rb4.x, cx1);
                float lty = fmaxf(rb4.y, cy1);
                float rbx = fminf(rb4.z, cx2);
                float rby = fminf(rb4.w, cy2);
                float w = fmaxf(rbx - ltx, 0.f);
                float h = fmaxf(rby - lty, 0.f);
                float inter = w * h;
                float iou = inter / (rarea + cak - inter + 1e-9f);
                bits |= (iou > 0.4f) ? (1ull << k) : 0ull;
            }
            u64 m = cvalid;
            if (cw == rb) m &= (lane == 63) ? 0ull : (~0ull << (lane + 1));
            bits &= (lgr > 0.f) ? m : 0ull;

            if (bits) {
                unsigned idx = atomicAdd(&p.cnt[r], 1u);
                if (idx < CAP) {
                    ulonglong2 e; e.x = bits; e.y = (u64)cw;
                    p.ent[(size_t)r * CAP + idx] = e;
                }
                atomicOr(&p.rowflag[r >> 6], 1ull << (r & 63));
            }
        }
    }
    grid.sync();

    // ---------------- Phase E: serial greedy resolve (block 0, wave 0) ----------------
    if (blockIdx.x == 0) {
        int lane = tid;   // only meaningful for tid<64
        u64 rf[3] = {0,0,0}, vw[3] = {0,0,0};
        int n_nz = 0;
        if (tid < 64) {
            #pragma unroll
            for (int s = 0; s < 3; ++s) {
                int w = s * 64 + lane;
                rf[s] = (w < MASK_WORDS) ? p.rowflag[w] : 0ull;
                vw[s] = (w < MASK_WORDS) ? p.validw[w] : 0ull;
            }
            int base = 0;
            #pragma unroll
            for (int s = 0; s < 3; ++s) {
                int c = (int)__popcll(rf[s]);
                int x = c;
                #pragma unroll
                for (int o = 1; o < 64; o <<= 1) { int y = __shfl_up(x, o); if (lane >= o) x += y; }
                int excl = x - c;
                int total = __shfl(x, 63);
                int off = base + excl;
                u64 tt = rf[s];
                int wbase = (s * 64 + lane) << 6;
                while (tt) {
                    int b = __builtin_ctzll(tt); tt &= tt - 1;
                    nlist[off++] = (unsigned short)(wbase | b);
                }
                base += total;
            }
            n_nz = base;
        }
        __syncthreads();
        if (tid < 64) {
            u64 rem0 = 0ull, rem1 = 0ull, rem2 = 0ull;
            if (n_nz > 0) {
                int half = lane >> 5;
                int sub  = lane & 31;
                int idx0 = min(sub, n_nz - 1);
                int rowCur = nlist[idx0];
                unsigned cntCur = p.cnt[rowCur];
                ulonglong2 entCur = p.ent[(size_t)rowCur * CAP + half];

                for (int k0 = 0; k0 < n_nz; k0 += 32) {
                    int nb = k0 + 32;
                    int rowNxt = 0; unsigned cntNxt = 0u;
                    ulonglong2 entNxt; entNxt.x = 0ull; entNxt.y = 0ull;
                    if (nb < n_nz) {
                        int idx = min(nb + sub, n_nz - 1);
                        rowNxt = nlist[idx];
                        cntNxt = p.cnt[rowNxt];
                        entNxt = p.ent[(size_t)rowNxt * CAP + half];
                    }
                    int lim = min(32, n_nz - k0);
                    for (int i = 0; i < lim; ++i) {
                        int r = __builtin_amdgcn_readlane(rowCur, i);
                        int w = r >> 6, slot = w >> 6, owner = w & 63, b = r & 63;
                        u64 rw = (slot == 0) ? rem0 : ((slot == 1) ? rem1 : rem2);
                        unsigned halfw = (b < 32) ? (unsigned)rw : (unsigned)(rw >> 32);
                        unsigned word = (unsigned)__builtin_amdgcn_readlane((int)halfw, owner);
                        if (!((word >> (b & 31)) & 1u)) {
                            unsigned c = (unsigned)__builtin_amdgcn_readlane((int)cntCur, i);
                            int ec = (int)min(c, 2u);
                            for (int e = 0; e < ec; ++e) {
                                int src = e * 32 + i;
                                unsigned ey  = (unsigned)__builtin_amdgcn_readlane((int)(unsigned)entCur.y, src);
                                unsigned blo = (unsigned)__builtin_amdgcn_readlane((int)(unsigned)entCur.x, src);
                                unsigned bhi = (unsigned)__builtin_amdgcn_readlane((int)(unsigned)(entCur.x >> 32), src);
                                u64 bits = ((u64)bhi << 32) | (u64)blo;
                                int es = (int)(ey >> 6), eo = (int)(ey & 63u);
                                u64 add = (lane == eo) ? bits : 0ull;
                                if (es == 0) rem0 |= add; else if (es == 1) rem1 |= add; else rem2 |= add;
                            }
                            if (c > 2u) {
                                unsigned cm = min(c, (unsigned)CAP);
                                for (unsigned e = 2; e < cm; ++e) {
                                    ulonglong2 g = p.ent[(size_t)r * CAP + e];
                                    int es = (int)(g.y >> 6), eo = (int)(g.y & 63u);
                                    u64 add = (lane == eo) ? g.x : 0ull;
                                    if (es == 0) rem0 |= add; else if (es == 1) rem1 |= add; else rem2 |= add;
                                }
                            }
                        }
                    }
                    rowCur = rowNxt; cntCur = cntNxt; entCur = entNxt;
                }
            }
            u64 rem[3] = {rem0, rem1, rem2};
            #pragma unroll
            for (int s = 0; s < 3; ++s) {
                int w = s * 64 + lane;
                if (w < MASK_WORDS) p.keep_words[w] = vw[s] & ~rem[s];
            }
        }
    }
    grid.sync();

    // ---------------- Phase F: write outputs ----------------
    if (gtid < N_TOT) {
        int r = gtid;
        float m = ((p.keep_words[r >> 6] >> (r & 63)) & 1ull) ? 1.0f : 0.0f;
        float* ob = p.out;                   // 8400*4
        float* os = p.out + 33600;           // 8400
        float* okp = p.out + 42000;          // 8400*10
        float* om = p.out + 126000;          // 8400
        #pragma unroll
        for (int c = 0; c < 4; ++c)  ob[r*4+c] = p.s_box[r*4+c] * m;
        os[r] = p.s_sig[r] * m;
        #pragma unroll
        for (int c = 0; c < 10; ++c) okp[r*10+c] = p.s_kps[r*10+c] * m;
        om[r] = m;
    }
}

extern "C" void kernel_launch(void* const* d_in, const int* in_sizes, int n_in,
                              void* d_out, int out_size, void* d_ws, size_t ws_size,
                              hipStream_t stream) {
    MegaParams p;
    if (in_sizes[1] == 25600) {
        p.score0 = (const float*)d_in[0]; p.bbox0 = (const float*)d_in[1]; p.kps0 = (const float*)d_in[2];
        p.score1 = (const float*)d_in[3]; p.bbox1 = (const float*)d_in[4]; p.kps1 = (const float*)d_in[5];
        p.score2 = (const float*)d_in[6]; p.bbox2 = (const float*)d_in[7]; p.kps2 = (const float*)d_in[8];
    } else {
        p.score0 = (const float*)d_in[0]; p.score1 = (const float*)d_in[1]; p.score2 = (const float*)d_in[2];
        p.bbox0  = (const float*)d_in[3]; p.bbox1  = (const float*)d_in[4]; p.bbox2  = (const float*)d_in[5];
        p.kps0   = (const float*)d_in[6]; p.kps1   = (const float*)d_in[7]; p.kps2   = (const float*)d_in[8];
    }

    char* ws = (char*)d_ws;
    p.logit   = (float*)(ws + 0);
    p.sig     = (float*)(ws + 33600);
    p.box     = (float*)(ws + 67200);
    p.kps     = (float*)(ws + 201600);
    p.rank    = (int*)  (ws + 537600);
    p.s_logit = (float*)(ws + 571200);
    p.s_sig   = (float*)(ws + 604800);
    p.s_box   = (float*)(ws + 638400);          // 16B-aligned (float4 loads)
    p.s_kps   = (float*)(ws + 772800);          // ends 1108800
    p.keep_words = (u64*)(ws + 1108800);        // 1056 B
    p.validw     = (u64*)(ws + 1110144);        // 1056 B
    p.rowflag    = (u64*)(ws + 1111296);        // 1056 B
    p.cnt = (unsigned int*)(ws + 1112448);      // 33600 B
    p.key = (u64*)(ws + 1146368);               // 67200 B
    p.ent = (ulonglong2*)(ws + 1213568);        // 8400*32*16 = 4.3 MB
    p.out = (float*)d_out;

    void* args[] = { &p };
    hipLaunchCooperativeKernel((const void*)mega_kernel, dim3(GRID), dim3(256), args, 0, stream);
}

// Round 7
// 135.526 us; speedup vs baseline: 2.0207x; 2.0207x over previous
//
#include <hip/hip_runtime.h>
#include <math.h>

#define N_TOT 8400
#define MASK_WORDS 132   // ceil(8400/64)
#define CAP 32           // max (word,bits) entries per row
#define RT 33            // rank tiles: ceil(8400/256)
#define PBLK 256         // persistent blocks for pairs

typedef unsigned long long u64;

// monotone-increasing float->u32 mapping
__device__ __forceinline__ unsigned mono_u32(float f) {
    unsigned u = __float_as_uint(f);
    return (u & 0x80000000u) ? ~u : (u | 0x80000000u);
}

// ---------------- K1: decode + build sort keys + zero-init state ----------------
__global__ void decode_kernel(const float* __restrict__ score0, const float* __restrict__ bbox0, const float* __restrict__ kps0,
                              const float* __restrict__ score1, const float* __restrict__ bbox1, const float* __restrict__ kps1,
                              const float* __restrict__ score2, const float* __restrict__ bbox2, const float* __restrict__ kps2,
                              float* __restrict__ logit, float* __restrict__ sig,
                              float* __restrict__ box, float* __restrict__ kps,
                              u64* __restrict__ key, int* __restrict__ rank,
                              unsigned int* __restrict__ cnt,
                              u64* __restrict__ validw, u64* __restrict__ rowflag,
                              int* __restrict__ nvalid) {
    int i = blockIdx.x * blockDim.x + threadIdx.x;
    if (i >= N_TOT) return;
    if (i == 0) *nvalid = 0;
    if (i < MASK_WORDS) { validw[i] = 0ull; rowflag[i] = 0ull; }
    rank[i] = 0;
    cnt[i] = 0u;
    const float *sc, *bb, *kp;
    int m, F; float s;
    if (i < 6400)      { sc = score0; bb = bbox0; kp = kps0; m = i;        F = 80; s = 8.f;  }
    else if (i < 8000) { sc = score1; bb = bbox1; kp = kps1; m = i - 6400; F = 40; s = 16.f; }
    else               { sc = score2; bb = bbox2; kp = kps2; m = i - 8000; F = 20; s = 32.f; }
    float px = (float)(m % F) * s;
    float py = (float)(m / F) * s;
    float lg = sc[m];
    logit[i] = lg;
    sig[i] = 1.0f / (1.0f + expf(-lg));
    key[i] = ((u64)(~mono_u32(lg)) << 14) | (u64)i;
    float d0 = bb[m*4+0]*s, d1 = bb[m*4+1]*s, d2 = bb[m*4+2]*s, d3 = bb[m*4+3]*s;
    box[i*4+0] = px - d0;
    box[i*4+1] = py - d1;
    box[i*4+2] = px + d2;
    box[i*4+3] = py + d3;
    #pragma unroll
    for (int c = 0; c < 5; ++c) {
        kps[i*10 + 2*c]   = px + kp[m*10 + 2*c]   * s;
        kps[i*10 + 2*c+1] = py + kp[m*10 + 2*c+1] * s;
    }
}

// ---------------- K2: tiled rank = #{j : key[j] < key[i]} ----------------
__global__ __launch_bounds__(256) void rank_kernel(const u64* __restrict__ key, int* __restrict__ rank) {
    __shared__ u64 tile[256];
    int i = blockIdx.x * 256 + threadIdx.x;
    int t0 = blockIdx.y * 256;
    u64 ki = (i < N_TOT) ? key[i] : 0ull;
    int j = t0 + threadIdx.x;
    tile[threadIdx.x] = (j < N_TOT) ? key[j] : ~0ull;   // OOB sorts last (never < ki)
    __syncthreads();
    if (i >= N_TOT) return;
    int rk = 0;
    #pragma unroll 8
    for (int k = 0; k < 256; ++k) {
        rk += (tile[k] < ki) ? 1 : 0;
    }
    if (rk) atomicAdd(&rank[i], rk);
}

// ---------------- K3: scatter into sorted order + valid bits + count V ----------------
__global__ __launch_bounds__(256) void scatter_kernel(const int* __restrict__ rank,
                               const float* __restrict__ logit, const float* __restrict__ sig,
                               const float* __restrict__ box, const float* __restrict__ kps,
                               float* __restrict__ s_logit, float* __restrict__ s_sig,
                               float* __restrict__ s_box, float* __restrict__ s_kps,
                               u64* __restrict__ validw, int* __restrict__ nvalid) {
    int i = blockIdx.x * blockDim.x + threadIdx.x;
    float lg = -1.f;
    if (i < N_TOT) {
        int r = rank[i];
        lg = logit[i];
        s_logit[r] = lg;
        s_sig[r] = sig[i];
        #pragma unroll
        for (int c = 0; c < 4; ++c)  s_box[r*4+c] = box[i*4+c];
        #pragma unroll
        for (int c = 0; c < 10; ++c) s_kps[r*10+c] = kps[i*10+c];
        if (lg > 0.f) atomicOr(&validw[r >> 6], 1ull << (r & 63));
    }
    u64 vb = __ballot(lg > 0.f);
    if ((threadIdx.x & 63) == 0 && vb) atomicAdd(nvalid, (int)__popcll(vb));
}

// ---------------- K4: sparse successor pairs — persistent waves over VALID triangle ----------------
__global__ __launch_bounds__(256) void pairs_kernel(const float* __restrict__ s_logit,
                                                    const float* __restrict__ s_box,
                                                    const int* __restrict__ nvalid,
                                                    unsigned int* __restrict__ cnt,
                                                    ulonglong2* __restrict__ ent,
                                                    u64* __restrict__ rowflag) {
    int wv = threadIdx.x >> 6;
    int lane = threadIdx.x & 63;
    int wgid = blockIdx.x * 4 + wv;
    const int V = *nvalid;                 // valid ranks are prefix [0,V)
    const int nw = (V + 63) >> 6;          // active words
    const int T = nw * (nw + 1) / 2;       // triangle tiles (rb<=cw<nw)
    const float4* sbox4 = (const float4*)s_box;

    for (int t = wgid; t < T; t += PBLK * 4) {
        // t -> (rb, cw): S(rb) = rb*nw - rb(rb-1)/2, find rb with S(rb)<=t<S(rb+1)
        float fn = (float)nw + 0.5f;
        int rb = (int)(fn - sqrtf(fn * fn - 2.0f * (float)t));
        if (rb < 0) rb = 0;
        while (rb > 0 && (rb * nw - (rb * (rb - 1)) / 2) > t) --rb;
        while (((rb + 1) * nw - ((rb + 1) * rb) / 2) <= t) ++rb;
        int cw = rb + (t - (rb * nw - (rb * (rb - 1)) / 2));

        int j = cw * 64 + lane;
        float4 cb = make_float4(0.f, 0.f, 0.f, 0.f);
        bool cval = (j < V);               // prefix validity: rank<V <=> logit>0
        if (j < N_TOT) cb = sbox4[j];
        u64 cvalid = __ballot(cval);

        int r = rb * 64 + lane;
        bool rval = (r < V);

        float4 rb4 = (r < N_TOT) ? sbox4[r] : make_float4(0.f, 0.f, 0.f, 0.f);
        float rarea = (rb4.z - rb4.x) * (rb4.w - rb4.y);
        float ca = (cb.z - cb.x) * (cb.w - cb.y);
        u64 bits = 0ull;
        #pragma unroll 4
        for (int k = 0; k < 64; ++k) {     // all lanes active -> shfl well-defined
            float cx1 = __shfl(cb.x, k);
            float cy1 = __shfl(cb.y, k);
            float cx2 = __shfl(cb.z, k);
            float cy2 = __shfl(cb.w, k);
            float cak = __shfl(ca, k);
            float ltx = fmaxf(rb4.x, cx1);
            float lty = fmaxf(rb4.y, cy1);
            float rbx = fminf(rb4.z, cx2);
            float rby = fminf(rb4.w, cy2);
            float w = fmaxf(rbx - ltx, 0.f);
            float h = fmaxf(rby - lty, 0.f);
            float inter = w * h;
            float iou = inter / (rarea + cak - inter + 1e-9f);
            bits |= (iou > 0.4f) ? (1ull << k) : 0ull;
        }
        u64 m = cvalid;
        if (cw == rb) m &= (lane == 63) ? 0ull : (~0ull << (lane + 1));  // strict successors
        bits &= rval ? m : 0ull;

        if (bits) {
            unsigned idx = atomicAdd(&cnt[r], 1u);
            if (idx < CAP) {
                ulonglong2 e; e.x = bits; e.y = (u64)cw;
                ent[(size_t)r * CAP + idx] = e;
            }
            atomicOr(&rowflag[r >> 6], 1ull << (r & 63));
        }
    }
}

// ---------------- K5: serial greedy resolve (wave 0) + fused output (256 thr) ----------------
__global__ __launch_bounds__(256) void nms_output_kernel(const u64* __restrict__ rowflag_g,
                                                         const u64* __restrict__ validw_g,
                                                         const unsigned int* __restrict__ cnt_g,
                                                         const ulonglong2* __restrict__ ent_g,
                                                         const float* __restrict__ s_sig,
                                                         const float* __restrict__ s_box,
                                                         const float* __restrict__ s_kps,
                                                         float* __restrict__ out) {
    __shared__ unsigned short nlist[8448];
    __shared__ u64 keepw[MASK_WORDS];
    int tid = threadIdx.x;

    if (tid < 64) {
        int lane = tid;
        u64 rf[3], vw[3];
        #pragma unroll
        for (int s = 0; s < 3; ++s) {
            int w = s * 64 + lane;
            rf[s] = (w < MASK_WORDS) ? rowflag_g[w] : 0ull;
            vw[s] = (w < MASK_WORDS) ? validw_g[w] : 0ull;
        }
        // sorted nonzero-row list via wave prefix sums
        int base = 0;
        #pragma unroll
        for (int s = 0; s < 3; ++s) {
            int c = (int)__popcll(rf[s]);
            int x = c;
            #pragma unroll
            for (int o = 1; o < 64; o <<= 1) { int y = __shfl_up(x, o); if (lane >= o) x += y; }
            int excl = x - c;
            int total = __shfl(x, 63);
            int off = base + excl;
            u64 t = rf[s];
            int wbase = (s * 64 + lane) << 6;
            while (t) {
                int b = __builtin_ctzll(t); t &= t - 1;
                nlist[off++] = (unsigned short)(wbase | b);
            }
            base += total;
        }
        int n_nz = base;

        u64 rem0 = 0ull, rem1 = 0ull, rem2 = 0ull;
        if (n_nz > 0) {
            int half = lane >> 5;
            int sub  = lane & 31;
            int idx0 = min(sub, n_nz - 1);
            int rowCur = nlist[idx0];
            unsigned cntCur = cnt_g[rowCur];
            ulonglong2 entCur = ent_g[(size_t)rowCur * CAP + half];

            for (int k0 = 0; k0 < n_nz; k0 += 32) {
                int nb = k0 + 32;
                int rowNxt = 0; unsigned cntNxt = 0u;
                ulonglong2 entNxt; entNxt.x = 0ull; entNxt.y = 0ull;
                if (nb < n_nz) {
                    int idx = min(nb + sub, n_nz - 1);
                    rowNxt = nlist[idx];
                    cntNxt = cnt_g[rowNxt];
                    entNxt = ent_g[(size_t)rowNxt * CAP + half];
                }
                int lim = min(32, n_nz - k0);
                for (int i = 0; i < lim; ++i) {
                    int r = __builtin_amdgcn_readlane(rowCur, i);
                    int w = r >> 6, slot = w >> 6, owner = w & 63, b = r & 63;
                    u64 rw = (slot == 0) ? rem0 : ((slot == 1) ? rem1 : rem2);
                    unsigned halfw = (b < 32) ? (unsigned)rw : (unsigned)(rw >> 32);
                    unsigned word = (unsigned)__builtin_amdgcn_readlane((int)halfw, owner);
                    if (!((word >> (b & 31)) & 1u)) {
                        unsigned c = (unsigned)__builtin_amdgcn_readlane((int)cntCur, i);
                        int ec = (int)min(c, 2u);
                        for (int e = 0; e < ec; ++e) {
                            int src = e * 32 + i;
                            unsigned ey  = (unsigned)__builtin_amdgcn_readlane((int)(unsigned)entCur.y, src);
                            unsigned blo = (unsigned)__builtin_amdgcn_readlane((int)(unsigned)entCur.x, src);
                            unsigned bhi = (unsigned)__builtin_amdgcn_readlane((int)(unsigned)(entCur.x >> 32), src);
                            u64 bits = ((u64)bhi << 32) | (u64)blo;
                            int es = (int)(ey >> 6), eo = (int)(ey & 63u);
                            u64 add = (lane == eo) ? bits : 0ull;
                            if (es == 0) rem0 |= add; else if (es == 1) rem1 |= add; else rem2 |= add;
                        }
                        if (c > 2u) {
                            unsigned cm = min(c, (unsigned)CAP);
                            for (unsigned e = 2; e < cm; ++e) {
                                ulonglong2 g = ent_g[(size_t)r * CAP + e];
                                int es = (int)(g.y >> 6), eo = (int)(g.y & 63u);
                                u64 add = (lane == eo) ? g.x : 0ull;
                                if (es == 0) rem0 |= add; else if (es == 1) rem1 |= add; else rem2 |= add;
                            }
                        }
                    }
                }
                rowCur = rowNxt; cntCur = cntNxt; entCur = entNxt;
            }
        }
        u64 rem[3] = {rem0, rem1, rem2};
        #pragma unroll
        for (int s = 0; s < 3; ++s) {
            int w = s * 64 + lane;
            if (w < MASK_WORDS) keepw[w] = vw[s] & ~rem[s];
        }
    }
    __syncthreads();

    // fused output: all 256 threads
    float* ob = out;                   // 8400*4
    float* os = out + 33600;           // 8400
    float* okp = out + 42000;          // 8400*10
    float* om = out + 126000;          // 8400
    for (int r = tid; r < N_TOT; r += 256) {
        float m = ((keepw[r >> 6] >> (r & 63)) & 1ull) ? 1.0f : 0.0f;
        float4 b4 = ((const float4*)s_box)[r];
        b4.x *= m; b4.y *= m; b4.z *= m; b4.w *= m;
        ((float4*)ob)[r] = b4;
        os[r] = s_sig[r] * m;
        #pragma unroll
        for (int c = 0; c < 10; ++c) okp[r*10+c] = s_kps[r*10+c] * m;
        om[r] = m;
    }
}

extern "C" void kernel_launch(void* const* d_in, const int* in_sizes, int n_in,
                              void* d_out, int out_size, void* d_ws, size_t ws_size,
                              hipStream_t stream) {
    const float *score0, *bbox0, *kps0, *score1, *bbox1, *kps1, *score2, *bbox2, *kps2;
    if (in_sizes[1] == 25600) {
        score0 = (const float*)d_in[0]; bbox0 = (const float*)d_in[1]; kps0 = (const float*)d_in[2];
        score1 = (const float*)d_in[3]; bbox1 = (const float*)d_in[4]; kps1 = (const float*)d_in[5];
        score2 = (const float*)d_in[6]; bbox2 = (const float*)d_in[7]; kps2 = (const float*)d_in[8];
    } else {
        score0 = (const float*)d_in[0]; score1 = (const float*)d_in[1]; score2 = (const float*)d_in[2];
        bbox0  = (const float*)d_in[3]; bbox1  = (const float*)d_in[4]; bbox2  = (const float*)d_in[5];
        kps0   = (const float*)d_in[6]; kps1   = (const float*)d_in[7]; kps2   = (const float*)d_in[8];
    }

    char* ws = (char*)d_ws;
    float* logit   = (float*)(ws + 0);
    float* sig     = (float*)(ws + 33600);
    float* box     = (float*)(ws + 67200);
    float* kps     = (float*)(ws + 201600);
    int*   rank    = (int*)  (ws + 537600);
    float* s_logit = (float*)(ws + 571200);
    float* s_sig   = (float*)(ws + 604800);
    float* s_box   = (float*)(ws + 638400);          // 16B-aligned (float4 loads)
    float* s_kps   = (float*)(ws + 772800);          // ends 1108800
    u64*   keep_words = (u64*)(ws + 1108800);        // (unused now, kept for layout)
    u64*   validw     = (u64*)(ws + 1110144);        // 1056 B
    u64*   rowflag    = (u64*)(ws + 1111296);        // 1056 B
    int*   nvalid     = (int*)(ws + 1112384);        // 4 B
    unsigned int* cnt = (unsigned int*)(ws + 1112448);   // 33600 B
    u64*   key        = (u64*)(ws + 1146368);            // 67200 B
    ulonglong2*   ent = (ulonglong2*)(ws + 1213568);     // 8400*32*16 = 4.3 MB
    (void)keep_words;

    float* out = (float*)d_out;

    decode_kernel<<<(N_TOT + 255) / 256, 256, 0, stream>>>(
        score0, bbox0, kps0, score1, bbox1, kps1, score2, bbox2, kps2,
        logit, sig, box, kps, key, rank, cnt, validw, rowflag, nvalid);
    rank_kernel<<<dim3(RT, RT), 256, 0, stream>>>(key, rank);
    scatter_kernel<<<33, 256, 0, stream>>>(rank, logit, sig, box, kps,
                                           s_logit, s_sig, s_box, s_kps, validw, nvalid);
    pairs_kernel<<<PBLK, 256, 0, stream>>>(s_logit, s_box, nvalid, cnt, ent, rowflag);
    nms_output_kernel<<<1, 256, 0, stream>>>(rowflag, validw, cnt, ent,
                                             s_sig, s_box, s_kps, out);
}